// Round 8
// baseline (95.411 us; speedup 1.0000x reference)
//
#include <hip/hip_runtime.h>
#include <hip/hip_bf16.h>

#define BATCH 8192
#define DIN   4096
#define H1    128
#define NLAT  512
#define LAT   32
#define BM    16
#define BKW   64            // per-step K columns (per wave)
#define WSTEPS 16           // 1024 / BKW; per-wave K-range = 1024
#define ABUF  1024          // 16 rows * 64 ushorts per private buffer

typedef short bf16x8 __attribute__((ext_vector_type(8)));
typedef float f32x4  __attribute__((ext_vector_type(4)));

static __device__ __forceinline__ unsigned short f2bf(float f) {
  union { float f; unsigned u; } v; v.f = f;
  return (unsigned short)((v.u + 0x7FFFu + ((v.u >> 16) & 1u)) >> 16);  // RNE
}

static __device__ __forceinline__ void cvtw8(unsigned short* p, f32x4 a, f32x4 b) {
  union { bf16x8 v; unsigned short u[8]; } o;
#pragma unroll
  for (int j = 0; j < 4; j++) { o.u[j] = f2bf(a[j]); o.u[4 + j] = f2bf(b[j]); }
  *(bf16x8*)p = o.v;
}

// ---- prep_all: W1 -> W1B frag-packed bf16; W2 -> W2B frag-packed bf16;
// decoders -> decT [32][4096] f32. Fragment packing (gi = k32*NCF + cf):
// elem j of lane (g=lane>>4, fr=lane&15) holds W[k32*32+g*8+j][cf*16+fr],
// so a wave's fragment load is one contiguous 1KB dwordx4. ----
__global__ void prep_all(const float* __restrict__ W1, const float* __restrict__ W2,
                         const float* __restrict__ dec,
                         unsigned short* __restrict__ W1B,
                         unsigned short* __restrict__ W2B,
                         float* __restrict__ decT) {
  int b = blockIdx.x;
  int t = threadIdx.x;
  if (b < 256) {
    int gi = (b << 2) + (t >> 6);         // k32*8 + cf, 0..1023
    int lane = t & 63;
    int kb = ((gi >> 3) << 5) + ((lane >> 4) << 3);
    int c = ((gi & 7) << 4) + (lane & 15);
    union { bf16x8 v; unsigned short u[8]; } o;
#pragma unroll
    for (int j = 0; j < 8; j++) o.u[j] = f2bf(W1[(size_t)(kb + j) * H1 + c]);
    *(bf16x8*)(W1B + (((size_t)gi << 6) + lane) * 8) = o.v;
  } else if (b < 288) {
    int gi = ((b - 256) << 2) + (t >> 6); // k32*32 + cf, 0..127
    int lane = t & 63;
    int kb = ((gi >> 5) << 5) + ((lane >> 4) << 3);
    int c = ((gi & 31) << 4) + (lane & 15);
    union { bf16x8 v; unsigned short u[8]; } o;
#pragma unroll
    for (int j = 0; j < 8; j++) o.u[j] = f2bf(W2[(size_t)(kb + j) * NLAT + c]);
    *(bf16x8*)(W2B + (((size_t)gi << 6) + lane) * 8) = o.v;
  } else {
    __shared__ float tbuf[32][33];
    int d0 = (b - 288) * 32;
    int tx = t & 31, ty = t >> 5;
#pragma unroll
    for (int i = 0; i < 32; i += 8)
      tbuf[ty + i][tx] = dec[(size_t)(d0 + ty + i) * LAT + tx];
    __syncthreads();
#pragma unroll
    for (int i = 0; i < 32; i += 8)
      decT[(size_t)(ty + i) * DIN + (d0 + tx)] = tbuf[tx][ty + i];
  }
}

// ---- enc_kernel: h = relu(x@W1+b1); z = h@W2+b2 -> zout; zsum -> zsumg.
// 4 waves x 16 rows. Phase A is BARRIER-FREE: each wave owns K-range
// w*1024..+1024, stages its own 16x64 f32 tile into wave-private LDS
// (coalesced 64B/lane, f2bf, XOR-swizzled 16B granules), computes partial
// acc over all 128 cols. Wave-internal ds ordering needs only lgkmcnt ->
// loads stay in flight across steps (no vmcnt(0) barrier drain).
// One barrier: reduce 4 partial-h + bias + relu -> hs; then phase B. ----
__global__ __launch_bounds__(256, 2) void enc_kernel(
    const float* __restrict__ x, const unsigned short* __restrict__ W1B,
    const unsigned short* __restrict__ W2B,
    const float* __restrict__ b1, const float* __restrict__ b2,
    float* __restrict__ zout, float* __restrict__ zsumg) {
  __shared__ unsigned short Apriv[4 * 2 * ABUF];  // 16 KB: per-wave dbuf
  __shared__ unsigned short hs[16 * 128];         // 4 KB, XOR-swizzled
  __shared__ float pacc[4][16][132];              // 33 KB partial h
  __shared__ float zsp[4][16][33];                // 8.4 KB

  const int t = threadIdx.x;
  const int rbase = blockIdx.x << 4;
  const int w = t >> 6, lane = t & 63;
  const int g = lane >> 4, fr = lane & 15;

  // ---- phase A (barrier-free) ----
  const int srow = lane >> 2, sq = lane & 3;      // 4 lanes/row, 16 f32 each
  const int k0 = w << 10;
  const float* xp = x + (size_t)(rbase + srow) * DIN + k0 + (sq << 4);
  unsigned short* abase = Apriv + (w << 11);      // w * 2*ABUF
  const int wg0 = ((sq << 1) ^ (srow & 7)) << 3;  // swizzled granule offsets
  const int wg1 = (((sq << 1) | 1) ^ (srow & 7)) << 3;
  unsigned short* wrow = abase + srow * 64;

  f32x4 acc[8];
#pragma unroll
  for (int i = 0; i < 8; i++) acc[i] = (f32x4){0.f, 0.f, 0.f, 0.f};

  // prologue: stage step 0 into buf 0
  {
    f32x4 q0 = *(const f32x4*)xp;
    f32x4 q1 = *(const f32x4*)(xp + 4);
    f32x4 q2 = *(const f32x4*)(xp + 8);
    f32x4 q3 = *(const f32x4*)(xp + 12);
    cvtw8(wrow + wg0, q0, q1);
    cvtw8(wrow + wg1, q2, q3);
  }

  for (int s = 0; s < WSTEPS; ++s) {
    f32x4 q0, q1, q2, q3;
    const bool more = (s + 1) < WSTEPS;
    if (more) {  // issue next-step loads before compute; no barrier ever
      const float* np = xp + (s + 1) * BKW;
      q0 = *(const f32x4*)np;
      q1 = *(const f32x4*)(np + 4);
      q2 = *(const f32x4*)(np + 8);
      q3 = *(const f32x4*)(np + 12);
    }
    const unsigned short* ab = abase + (s & 1) * ABUF;
    const int kbase = (w << 5) + (s << 1);        // global k32 base
#pragma unroll
    for (int k32l = 0; k32l < 2; ++k32l) {
      bf16x8 a = *(const bf16x8*)(ab + fr * 64 +
                   ((((k32l << 2) + g) ^ (fr & 7)) << 3));
      const unsigned short* bp = W1B + (((size_t)(kbase + k32l) << 3) << 9) + (lane << 3);
#pragma unroll
      for (int cf = 0; cf < 8; ++cf) {
        bf16x8 bv = *(const bf16x8*)(bp + ((size_t)cf << 9));
        acc[cf] = __builtin_amdgcn_mfma_f32_16x16x32_bf16(a, bv, acc[cf], 0, 0, 0);
      }
    }
    if (more) {
      unsigned short* wr = abase + ((s + 1) & 1) * ABUF + srow * 64;
      cvtw8(wr + wg0, q0, q1);
      cvtw8(wr + wg1, q2, q3);
    }
  }

  // write partial acc -> pacc. C/D: col=fr, row=g*4+j.
#pragma unroll
  for (int cf = 0; cf < 8; ++cf)
#pragma unroll
    for (int j = 0; j < 4; ++j)
      pacc[w][(g << 2) + j][(cf << 4) + fr] = acc[cf][j];
  __syncthreads();

  // reduce + b1 + relu -> hs (bf16, XOR-swizzled 16 granules/row)
  {
    const int r = t >> 4, c8 = (t & 15) << 3;
    f32x4 s0, s1;
#pragma unroll
    for (int j = 0; j < 4; j++) { s0[j] = b1[c8 + j]; s1[j] = b1[c8 + 4 + j]; }
#pragma unroll
    for (int wv = 0; wv < 4; ++wv) {
      f32x4 p0 = *(const f32x4*)&pacc[wv][r][c8];
      f32x4 p1 = *(const f32x4*)&pacc[wv][r][c8 + 4];
#pragma unroll
      for (int j = 0; j < 4; j++) { s0[j] += p0[j]; s1[j] += p1[j]; }
    }
#pragma unroll
    for (int j = 0; j < 4; j++) { s0[j] = fmaxf(s0[j], 0.f); s1[j] = fmaxf(s1[j], 0.f); }
    cvtw8(hs + (r << 7) + (((t & 15) ^ (r & 15)) << 3), s0, s1);
  }
  __syncthreads();

  // ---- phase B: z = h @ W2 + b2. Wave w: 16 rows x cols w*128..+128. ----
  f32x4 acc2[8];
#pragma unroll
  for (int i = 0; i < 8; i++) acc2[i] = (f32x4){0.f, 0.f, 0.f, 0.f};
#pragma unroll
  for (int k32 = 0; k32 < 4; ++k32) {
    bf16x8 a0 = *(const bf16x8*)(hs + (fr << 7) +
                  ((((k32 << 2) + g) ^ (fr & 15)) << 3));
#pragma unroll
    for (int cc = 0; cc < 8; ++cc) {
      bf16x8 bv = *(const bf16x8*)(W2B +
          (((size_t)((k32 << 5) + (w << 3) + cc)) << 9) + (lane << 3));
      acc2[cc] = __builtin_amdgcn_mfma_f32_16x16x32_bf16(a0, bv, acc2[cc], 0, 0, 0);
    }
  }

  // epilogue: z write + zsum fold. col = w*128 + cc*16 + fr;
  // latent l = (cc&1)*16 + fr; factor = w*4 + cc/2.
  {
    f32x4 zv[8];
#pragma unroll
    for (int cc = 0; cc < 8; ++cc) {
      const float b2v = b2[(w << 7) + (cc << 4) + fr];
#pragma unroll
      for (int j = 0; j < 4; j++) zv[cc][j] = acc2[cc][j] + b2v;
    }
    const int row0 = g << 2;
#pragma unroll
    for (int j = 0; j < 4; j++) {
#pragma unroll
      for (int cc = 0; cc < 8; ++cc)
        zout[(size_t)(rbase + row0 + j) * NLAT + (w << 7) + (cc << 4) + fr] = zv[cc][j];
      zsp[w][row0 + j][fr]      = zv[0][j] + zv[2][j] + zv[4][j] + zv[6][j];
      zsp[w][row0 + j][16 + fr] = zv[1][j] + zv[3][j] + zv[5][j] + zv[7][j];
    }
  }
  __syncthreads();
#pragma unroll
  for (int i = 0; i < 2; i++) {
    int idx = t + (i << 8);
    int r = idx >> 5, l = idx & 31;
    float s = zsp[0][r][l] + zsp[1][r][l] + zsp[2][r][l] + zsp[3][r][l];
    zsumg[(size_t)(rbase + r) * LAT + l] = s;
  }
}

// ---- recon_kernel: rout[b][d] = sum_l zsum[b][l] * decT[l][d]. ----
__global__ __launch_bounds__(256) void recon_kernel(
    const float* __restrict__ zsumg, const float* __restrict__ decT,
    float* __restrict__ rout) {
  __shared__ float zs[32][32];
  int t = threadIdx.x;
  int rbase = (blockIdx.x >> 4) << 5;
  int dcol0 = (blockIdx.x & 15) << 8;
  {
    int r = t >> 3, c4 = (t & 7) << 2;
    *(f32x4*)&zs[r][c4] = *(const f32x4*)(zsumg + (size_t)(rbase + r) * LAT + c4);
  }
  __syncthreads();
  int wq = t >> 6, lane = t & 63;
  int r0 = wq << 3;
  int dcol = dcol0 + (lane << 2);
  f32x4 acc[8];
#pragma unroll
  for (int r = 0; r < 8; r++) acc[r] = (f32x4){0.f, 0.f, 0.f, 0.f};
#pragma unroll 4
  for (int l = 0; l < 32; l++) {
    f32x4 dv = *(const f32x4*)(decT + (size_t)l * DIN + dcol);
#pragma unroll
    for (int r = 0; r < 8; r++) {
      float zv = zs[r0 + r][l];
#pragma unroll
      for (int j = 0; j < 4; j++) acc[r][j] += zv * dv[j];
    }
  }
#pragma unroll
  for (int r = 0; r < 8; r++)
    *(f32x4*)(rout + (size_t)(rbase + r0 + r) * DIN + dcol) = acc[r];
}

extern "C" void kernel_launch(void* const* d_in, const int* in_sizes, int n_in,
                              void* d_out, int out_size, void* d_ws, size_t ws_size,
                              hipStream_t stream) {
  const float* x   = (const float*)d_in[0];
  const float* W1  = (const float*)d_in[1];
  const float* b1  = (const float*)d_in[2];
  const float* W2  = (const float*)d_in[3];
  const float* b2  = (const float*)d_in[4];
  const float* dec = (const float*)d_in[5];
  float* zout = (float*)d_out;
  float* rout = zout + (size_t)BATCH * NLAT;

  char* ws = (char*)d_ws;
  unsigned short* W1B = (unsigned short*)ws;                          // 1 MB
  unsigned short* W2B = (unsigned short*)(ws + (1u << 20));           // 128 KB
  float* decT  = (float*)(ws + (1u << 20) + (1u << 17));              // 512 KB
  float* zsumg = (float*)(ws + (1u << 20) + (1u << 17) + (1u << 19)); // 1 MB

  prep_all<<<dim3(416), 256, 0, stream>>>(W1, W2, dec, W1B, W2B, decT);
  enc_kernel<<<dim3(BATCH / BM), 256, 0, stream>>>(x, W1B, W2B, b1, b2, zout, zsumg);
  recon_kernel<<<dim3(4096), 256, 0, stream>>>(zsumg, decT, rout);
}